// Round 15
// baseline (206.292 us; speedup 1.0000x reference)
//
#include <hip/hip_runtime.h>
#include <hip/hip_bf16.h>
#include <math.h>

#define NPOS 32768   // H*W*Z = 64*64*8

typedef __hip_bfloat16 bf16;
typedef __attribute__((ext_vector_type(8))) short bf16x8;
typedef __attribute__((ext_vector_type(4))) float f32x4;

__device__ __forceinline__ float bf2f(short s) {
    union { unsigned u; float f; } cv;
    cv.u = ((unsigned)(unsigned short)s) << 16;
    return cv.f;
}

// ---------------- all 4 weight transposes in ONE kernel: src[K][M] -> dst[M][K] bf16 ----------------
__global__ __launch_bounds__(256) void prep_weights_kernel(
    const float* __restrict__ qkv_w, const float* __restrict__ proj_w,
    const float* __restrict__ w1, const float* __restrict__ w2,
    bf16* __restrict__ wt_qkv, bf16* __restrict__ wt_proj,
    bf16* __restrict__ wt_w1, bf16* __restrict__ wt_w2)
{
    int bi = blockIdx.x;
    const float* src; bf16* dst; int K, M, t;
    if (bi < 48)       { src = qkv_w;  dst = wt_qkv;  K = 128; M = 384; t = bi; }
    else if (bi < 64)  { src = proj_w; dst = wt_proj; K = 128; M = 128; t = bi - 48; }
    else if (bi < 128) { src = w1;     dst = wt_w1;   K = 128; M = 512; t = bi - 64; }
    else               { src = w2;     dst = wt_w2;   K = 512; M = 128; t = bi - 128; }
    int tiles_x = M >> 5;
    int m0 = (t % tiles_x) * 32, k0 = (t / tiles_x) * 32;
    __shared__ float tile[32][33];
    int tx = threadIdx.x & 31, ty = threadIdx.x >> 5;
    #pragma unroll
    for (int i = 0; i < 4; i++)
        tile[ty + i * 8][tx] = src[(size_t)(k0 + ty + i * 8) * M + m0 + tx];
    __syncthreads();
    #pragma unroll
    for (int i = 0; i < 4; i++)
        dst[(size_t)(m0 + ty + i * 8) * K + k0 + tx] = __float2bfloat16(tile[tx][ty + i * 8]);
}

// ---------------- LN1: transpose (C,N)->(N,C) + layernorm over C, out bf16 ----------------
__global__ __launch_bounds__(256) void ln1_transpose_kernel(
    const float* __restrict__ x, const float* __restrict__ g,
    const float* __restrict__ b, bf16* __restrict__ out)
{
    __shared__ float tile[128][65];
    __shared__ float red[2][64][4];
    __shared__ float smu[64], srs[64];
    int n0 = blockIdx.x * 64;
    int tid = threadIdx.x;
    #pragma unroll
    for (int i = 0; i < 32; i++) {
        int idx = i * 256 + tid;
        int c = idx >> 6, nn = idx & 63;
        tile[c][nn] = x[(size_t)c * NPOS + n0 + nn];
    }
    __syncthreads();
    {
        int p = tid >> 2, s = tid & 3;
        float sum = 0.f, ssq = 0.f;
        #pragma unroll
        for (int i = 0; i < 32; i++) {
            float v = tile[s * 32 + i][p];
            sum += v; ssq += v * v;
        }
        red[0][p][s] = sum; red[1][p][s] = ssq;
    }
    __syncthreads();
    if (tid < 64) {
        float s = red[0][tid][0] + red[0][tid][1] + red[0][tid][2] + red[0][tid][3];
        float q = red[1][tid][0] + red[1][tid][1] + red[1][tid][2] + red[1][tid][3];
        float mu = s * (1.f / 128.f);
        float var = q * (1.f / 128.f) - mu * mu;
        smu[tid] = mu;
        srs[tid] = rsqrtf(var + 1e-5f);
    }
    __syncthreads();
    #pragma unroll
    for (int i = 0; i < 32; i++) {
        int idx = i * 256 + tid;
        int nn = idx >> 7, c = idx & 127;
        out[(size_t)(n0 + nn) * 128 + c] =
            __float2bfloat16((tile[c][nn] - smu[nn]) * srs[nn] * g[c] + b[c]);
    }
}

// ---------------- bf16 MFMA GEMM, BK=64, software-pipelined staging ----------------
// MODE 0: bf16 outb = acc + bias                     (QKV)
// MODE 4: proj+LN2: v=acc+bias+aux0[c*N+r]; outb(x1,bf16)[r*128+c]=v; row-LN(v) -> outb2 bf16
__device__ __forceinline__ float gelu_f(float v) {
    float u = 0.7978845608028654f * (v + 0.044715f * v * v * v);
    return v / (1.f + __expf(-2.f * u));
}

template<int MODE, int KT, int BM>
__global__ __launch_bounds__(256) void gemm_mfma_kernel(
    const bf16* __restrict__ A, const bf16* __restrict__ Bt,
    const float* __restrict__ bias, bf16* __restrict__ outb,
    bf16* __restrict__ outb2,
    const float* __restrict__ aux0,
    const float* __restrict__ lng, const float* __restrict__ lnb,
    int N, int M)
{
    constexpr int MF = BM / 32;
    constexpr int NSTEP = KT / 64;
    constexpr int SMEM_BYTES = BM * 144 + 128 * 144;
    __shared__ __align__(16) char smem[SMEM_BYTES];
    bf16 (*As)[72] = (bf16(*)[72])smem;
    bf16 (*Bs)[72] = (bf16(*)[72])(smem + BM * 144);

    int tid = threadIdx.x;
    int row0 = blockIdx.x * BM;
    int col0 = blockIdx.y * 128;
    int lane = tid & 63, wid = tid >> 6;
    int wr = wid >> 1, wc = wid & 1;
    int lr = lane & 15, kg = lane >> 4;

    f32x4 acc[MF][4] = {};
    bf16x8 ra[MF], rb[4];

    #pragma unroll
    for (int i = 0; i < MF; i++) {
        int c = tid + i * 256;
        ra[i] = *(const bf16x8*)(A + (size_t)(row0 + (c >> 3)) * KT + (c & 7) * 8);
    }
    #pragma unroll
    for (int i = 0; i < 4; i++) {
        int c = tid + i * 256;
        rb[i] = *(const bf16x8*)(Bt + (size_t)(col0 + (c >> 3)) * KT + (c & 7) * 8);
    }

    for (int s = 0; s < NSTEP; s++) {
        if (s > 0) __syncthreads();
        #pragma unroll
        for (int i = 0; i < MF; i++) {
            int c = tid + i * 256;
            *(bf16x8*)&As[c >> 3][(c & 7) * 8] = ra[i];
        }
        #pragma unroll
        for (int i = 0; i < 4; i++) {
            int c = tid + i * 256;
            *(bf16x8*)&Bs[c >> 3][(c & 7) * 8] = rb[i];
        }
        __syncthreads();
        if (s + 1 < NSTEP) {
            int k0 = (s + 1) * 64;
            #pragma unroll
            for (int i = 0; i < MF; i++) {
                int c = tid + i * 256;
                ra[i] = *(const bf16x8*)(A + (size_t)(row0 + (c >> 3)) * KT + k0 + (c & 7) * 8);
            }
            #pragma unroll
            for (int i = 0; i < 4; i++) {
                int c = tid + i * 256;
                rb[i] = *(const bf16x8*)(Bt + (size_t)(col0 + (c >> 3)) * KT + k0 + (c & 7) * 8);
            }
        }
        #pragma unroll
        for (int ks = 0; ks < 2; ks++) {
            bf16x8 af[MF], bf_[4];
            #pragma unroll
            for (int m = 0; m < MF; m++)
                af[m] = *(const bf16x8*)&As[wr * (BM / 2) + m * 16 + lr][ks * 32 + kg * 8];
            #pragma unroll
            for (int n = 0; n < 4; n++)
                bf_[n] = *(const bf16x8*)&Bs[wc * 64 + n * 16 + lr][ks * 32 + kg * 8];
            #pragma unroll
            for (int m = 0; m < MF; m++)
                #pragma unroll
                for (int n = 0; n < 4; n++)
                    acc[m][n] = __builtin_amdgcn_mfma_f32_16x16x32_bf16(af[m], bf_[n], acc[m][n], 0, 0, 0);
        }
    }

    if (MODE == 0) {
        #pragma unroll
        for (int m = 0; m < MF; m++) {
            #pragma unroll
            for (int n = 0; n < 4; n++) {
                int c = col0 + wc * 64 + n * 16 + lr;
                float bv = bias[c];
                #pragma unroll
                for (int j = 0; j < 4; j++) {
                    int r = row0 + wr * (BM / 2) + m * 16 + kg * 4 + j;
                    outb[(size_t)r * M + c] = __float2bfloat16(acc[m][n][j] + bv);
                }
            }
        }
    } else {
        // MODE 4: proj epilogue + fused LN2 (BM == 64, col0 == 0, M == 128 == full row)
        __syncthreads();
        float (*rsum)[33] = (float(*)[33])smem;               // 64*33*4 = 8448
        float (*rsq)[33]  = (float(*)[33])(smem + 8448);      // -> 16896
        float* smu = (float*)(smem + 16896);
        float* srs = (float*)(smem + 17152);
        int slot = wc * 16 + lr;
        #pragma unroll
        for (int m = 0; m < MF; m++) {
            #pragma unroll
            for (int j = 0; j < 4; j++) {
                int rloc = wr * (BM / 2) + m * 16 + kg * 4 + j;
                int r = row0 + rloc;
                float ps = 0.f, pq = 0.f;
                #pragma unroll
                for (int n = 0; n < 4; n++) {
                    int c = wc * 64 + n * 16 + lr;
                    float v = acc[m][n][j] + bias[c] + aux0[(size_t)c * N + r];
                    acc[m][n][j] = v;
                    outb[(size_t)r * 128 + c] = __float2bfloat16(v);   // x1 (bf16)
                    ps += v; pq += v * v;
                }
                rsum[rloc][slot] = ps;
                rsq[rloc][slot]  = pq;
            }
        }
        __syncthreads();
        if (tid < 64) {
            float s = 0.f, q = 0.f;
            #pragma unroll
            for (int i = 0; i < 32; i++) { s += rsum[tid][i]; q += rsq[tid][i]; }
            float mu = s * (1.f / 128.f);
            float var = q * (1.f / 128.f) - mu * mu;
            smu[tid] = mu;
            srs[tid] = rsqrtf(var + 1e-5f);
        }
        __syncthreads();
        #pragma unroll
        for (int m = 0; m < MF; m++) {
            #pragma unroll
            for (int j = 0; j < 4; j++) {
                int rloc = wr * (BM / 2) + m * 16 + kg * 4 + j;
                int r = row0 + rloc;
                float mu = smu[rloc], rs = srs[rloc];
                #pragma unroll
                for (int n = 0; n < 4; n++) {
                    int c = wc * 64 + n * 16 + lr;
                    float v = (acc[m][n][j] - mu) * rs * lng[c] + lnb[c];
                    outb2[(size_t)r * 128 + c] = __float2bfloat16(v);
                }
            }
        }
    }
}

// ---------------- fused MLP: skip = x1 + x + gelu(ln2 @ w1^T) @ w2^T (+biases) ----------------
// Block = 32 positions, 4 waves (2x2: wr rows, wc cols). Hidden kept in LDS only.
__global__ __launch_bounds__(256) void mlp_fused_kernel(
    const bf16* __restrict__ ln2,   // [N][128]
    const bf16* __restrict__ w1t,   // [512][128]
    const float* __restrict__ b1,
    const bf16* __restrict__ w2t,   // [128][512]
    const float* __restrict__ b2,
    const bf16* __restrict__ x1b,   // [N][128]
    const float* __restrict__ x,    // [C][N]
    float* __restrict__ skip,       // [C][N]
    int N)
{
    __shared__ __align__(16) bf16 As[32][136];   //  8704 B
    __shared__ __align__(16) bf16 Hs[32][520];   // 33280 B
    int tid = threadIdx.x;
    int row0 = blockIdx.x * 32;
    int lane = tid & 63, wid = tid >> 6;
    int wr = wid >> 1, wc = wid & 1;
    int lr = lane & 15, kg = lane >> 4;

    // stage ln2 rows (32 x 128 bf16 = 512 chunks of 16B)
    #pragma unroll
    for (int i = 0; i < 2; i++) {
        int c = tid + i * 256;
        int r = c >> 4, c16 = c & 15;
        *(bf16x8*)&As[r][c16 * 8] = *(const bf16x8*)(ln2 + (size_t)(row0 + r) * 128 + c16 * 8);
    }
    __syncthreads();

    // phase 1: hidden = gelu(ln2 @ w1t^T + b1), 4 col-blocks of 128
    #pragma unroll
    for (int cb = 0; cb < 4; cb++) {
        f32x4 acc[4] = {};
        #pragma unroll
        for (int k0 = 0; k0 < 128; k0 += 32) {
            bf16x8 af = *(const bf16x8*)&As[wr * 16 + lr][k0 + kg * 8];
            #pragma unroll
            for (int n = 0; n < 4; n++) {
                bf16x8 bf_ = *(const bf16x8*)(w1t + (size_t)(cb * 128 + wc * 64 + n * 16 + lr) * 128 + k0 + kg * 8);
                acc[n] = __builtin_amdgcn_mfma_f32_16x16x32_bf16(af, bf_, acc[n], 0, 0, 0);
            }
        }
        #pragma unroll
        for (int n = 0; n < 4; n++) {
            int c = cb * 128 + wc * 64 + n * 16 + lr;
            float bv = b1[c];
            #pragma unroll
            for (int j = 0; j < 4; j++) {
                int r = wr * 16 + kg * 4 + j;
                Hs[r][c] = __float2bfloat16(gelu_f(acc[n][j] + bv));
            }
        }
    }
    __syncthreads();

    // phase 2: out = hidden @ w2t^T + b2 + x1 + x -> skip (transposed f32)
    f32x4 acc2[4] = {};
    #pragma unroll
    for (int k0 = 0; k0 < 512; k0 += 32) {
        bf16x8 af = *(const bf16x8*)&Hs[wr * 16 + lr][k0 + kg * 8];
        #pragma unroll
        for (int n = 0; n < 4; n++) {
            bf16x8 bf_ = *(const bf16x8*)(w2t + (size_t)(wc * 64 + n * 16 + lr) * 512 + k0 + kg * 8);
            acc2[n] = __builtin_amdgcn_mfma_f32_16x16x32_bf16(af, bf_, acc2[n], 0, 0, 0);
        }
    }
    #pragma unroll
    for (int n = 0; n < 4; n++) {
        int c = wc * 64 + n * 16 + lr;
        float bv = b2[c];
        #pragma unroll
        for (int j = 0; j < 4; j++) {
            int r = row0 + wr * 16 + kg * 4 + j;
            float v = acc2[n][j] + bv + __bfloat162float(x1b[(size_t)r * 128 + c]) + x[(size_t)c * N + r];
            skip[(size_t)c * N + r] = v;
        }
    }
}

// ---------------- neighborhood attention: 1 thread per (position, head), NO LDS ----------------
__global__ __launch_bounds__(256) void attn_kernel(
    const bf16* __restrict__ qkv,   // [N][384]  (q|k|v)
    const float* __restrict__ rpb,  // [8][5][5][5]
    bf16* __restrict__ out)         // [N][128]
{
    int t = blockIdx.x * 256 + threadIdx.x;
    int head = t & 7, n = t >> 3;
    int z = n & 7, w = (n >> 3) & 63, h = n >> 9;

    int sh = min(max(h - 1, 0), 61);
    int sw = min(max(w - 1, 0), 61);
    int sz = min(max(z - 1, 0), 5);

    float qf[16];
    {
        const bf16* qp = qkv + (size_t)n * 384 + head * 16;
        bf16x8 q0 = *(const bf16x8*)qp;
        bf16x8 q1 = *(const bf16x8*)(qp + 8);
        #pragma unroll
        for (int e = 0; e < 8; e++) {
            qf[e]     = bf2f(q0[e]) * 0.25f;
            qf[e + 8] = bf2f(q1[e]) * 0.25f;
        }
    }

    const bf16*  kbase = qkv + (size_t)((sh << 9) + (sw << 3) + sz) * 384 + 128 + head * 16;
    const float* rp    = rpb + head * 125 + (sh - h + 2) * 25 + (sw - w + 2) * 5 + (sz - z + 2);

    float sc[27];
    float mx = -1e30f;
    #pragma unroll
    for (int a = 0; a < 3; a++) {
        #pragma unroll
        for (int b = 0; b < 3; b++) {
            #pragma unroll
            for (int c = 0; c < 3; c++) {
                const bf16* kp = kbase + (size_t)(a * 512 + b * 8 + c) * 384;
                bf16x8 k0 = *(const bf16x8*)kp;
                bf16x8 k1 = *(const bf16x8*)(kp + 8);
                float s = 0.f;
                #pragma unroll
                for (int e = 0; e < 8; e++) s = fmaf(qf[e], bf2f(k0[e]), s);
                #pragma unroll
                for (int e = 0; e < 8; e++) s = fmaf(qf[e + 8], bf2f(k1[e]), s);
                s += rp[a * 25 + b * 5 + c];
                sc[a * 9 + b * 3 + c] = s;
                mx = fmaxf(mx, s);
            }
        }
    }

    float sum = 0.f;
    #pragma unroll
    for (int m = 0; m < 27; m++) {
        float e = __expf(sc[m] - mx);
        sc[m] = e;
        sum += e;
    }
    float inv = 1.f / sum;

    float o[16] = {};
    #pragma unroll
    for (int a = 0; a < 3; a++) {
        #pragma unroll
        for (int b = 0; b < 3; b++) {
            #pragma unroll
            for (int c = 0; c < 3; c++) {
                const bf16* vp = kbase + (size_t)(a * 512 + b * 8 + c) * 384 + 128;
                bf16x8 v0 = *(const bf16x8*)vp;
                bf16x8 v1 = *(const bf16x8*)(vp + 8);
                float pm = sc[a * 9 + b * 3 + c];
                #pragma unroll
                for (int e = 0; e < 8; e++) {
                    o[e]     = fmaf(pm, bf2f(v0[e]), o[e]);
                    o[e + 8] = fmaf(pm, bf2f(v1[e]), o[e + 8]);
                }
            }
        }
    }

    short os[16];
    #pragma unroll
    for (int e = 0; e < 16; e++) {
        union { bf16 b; short s; } cv;
        cv.b = __float2bfloat16(o[e] * inv);
        os[e] = cv.s;
    }
    bf16* op = out + (size_t)n * 128 + head * 16;
    *(bf16x8*)op       = *(bf16x8*)os;
    *(bf16x8*)(op + 8) = *(bf16x8*)(os + 8);
}

// ---------------- 2x2x2 maxpool over (H,W,Z) ----------------
__global__ __launch_bounds__(256) void pool_kernel(
    const float* __restrict__ skip, float* __restrict__ pooled)
{
    int t = blockIdx.x * 256 + threadIdx.x;
    if (t >= 128 * 32 * 32 * 4) return;
    int oz = t & 3, ow = (t >> 2) & 31, oh = (t >> 7) & 31, c = t >> 12;
    const float* base = skip + (size_t)c * 32768 + (oh * 2) * 512 + (ow * 2) * 8 + oz * 2;
    float m = -INFINITY;
    #pragma unroll
    for (int dh = 0; dh < 2; dh++)
        #pragma unroll
        for (int dw = 0; dw < 2; dw++)
            #pragma unroll
            for (int dz = 0; dz < 2; dz++)
                m = fmaxf(m, base[dh * 512 + dw * 8 + dz]);
    pooled[t] = m;
}

extern "C" void kernel_launch(void* const* d_in, const int* in_sizes, int n_in,
                              void* d_out, int out_size, void* d_ws, size_t ws_size,
                              hipStream_t stream) {
    const float* x      = (const float*)d_in[0];
    const float* ln1_g  = (const float*)d_in[1];
    const float* ln1_b  = (const float*)d_in[2];
    const float* qkv_w  = (const float*)d_in[3];
    const float* qkv_b  = (const float*)d_in[4];
    const float* proj_w = (const float*)d_in[5];
    const float* proj_b = (const float*)d_in[6];
    const float* rpb    = (const float*)d_in[7];
    const float* ln2_g  = (const float*)d_in[8];
    const float* ln2_b  = (const float*)d_in[9];
    const float* w1     = (const float*)d_in[10];
    const float* b1     = (const float*)d_in[11];
    const float* w2     = (const float*)d_in[12];
    const float* b2     = (const float*)d_in[13];

    const int N = NPOS;
    char* wsc = (char*)d_ws;
    bf16*  buf0  = (bf16*)wsc;                               // N*128 bf16: xn -> attn_out -> ln2out
    bf16*  buf1  = (bf16*)(wsc + (size_t)N * 128 * 2);       // N*512 bf16: qkv(384)
    bf16*  buf2b = (bf16*)(wsc + (size_t)N * 128 * 2 + (size_t)N * 512 * 2);  // N*128 bf16: x1
    char*  wts   = wsc + (size_t)N * 128 * 2 + (size_t)N * 512 * 2 + (size_t)N * 128 * 2;
    bf16* wt_qkv  = (bf16*)wts;                 // [384][128]
    bf16* wt_proj = wt_qkv  + 384 * 128;        // [128][128]
    bf16* wt_w1   = wt_proj + 128 * 128;        // [512][128]
    bf16* wt_w2   = wt_w1   + 512 * 128;        // [128][512]

    float* out_pooled = (float*)d_out;
    float* out_skip   = (float*)d_out + 524288;

    // 0. all weight transposes in one launch
    prep_weights_kernel<<<192, 256, 0, stream>>>(qkv_w, proj_w, w1, w2,
                                                 wt_qkv, wt_proj, wt_w1, wt_w2);

    // 1. transpose + LN1 -> bf16
    ln1_transpose_kernel<<<N / 64, 256, 0, stream>>>(x, ln1_g, ln1_b, buf0);

    // 2. QKV GEMM: [N,128] @ [128,384] -> bf16
    gemm_mfma_kernel<0, 128, 128><<<dim3(N / 128, 3), 256, 0, stream>>>(
        buf0, wt_qkv, qkv_b, buf1, nullptr, nullptr, nullptr, nullptr, N, 384);

    // 3. neighborhood attention -> bf16 (no LDS, 1 thread per (pos,head))
    attn_kernel<<<(N * 8) / 256, 256, 0, stream>>>(buf1, rpb, buf0);

    // 4. proj GEMM + residual + fused LN2: x1(bf16)->buf2b, ln2out(bf16)->buf0
    gemm_mfma_kernel<4, 128, 64><<<dim3(N / 64, 1), 256, 0, stream>>>(
        buf0, wt_proj, proj_b, buf2b, buf0, x, ln2_g, ln2_b, N, 128);

    // 5+6. fused MLP: skip = x1 + x + gelu(ln2 @ w1^T + b1) @ w2^T + b2
    mlp_fused_kernel<<<N / 32, 256, 0, stream>>>(
        buf0, wt_w1, b1, wt_w2, b2, buf2b, x, out_skip, N);

    // 7. maxpool -> pooled
    pool_kernel<<<(524288 + 255) / 256, 256, 0, stream>>>(out_skip, out_pooled);
}

// Round 17
// 174.653 us; speedup vs baseline: 1.1812x; 1.1812x over previous
//
#include <hip/hip_runtime.h>
#include <hip/hip_bf16.h>
#include <math.h>

#define NPOS 32768   // H*W*Z = 64*64*8

typedef __hip_bfloat16 bf16;
typedef __attribute__((ext_vector_type(8))) short bf16x8;
typedef __attribute__((ext_vector_type(4))) float f32x4;

__device__ __forceinline__ float bf2f(short s) {
    union { unsigned u; float f; } cv;
    cv.u = ((unsigned)(unsigned short)s) << 16;
    return cv.f;
}

// ---------------- merged front-end: weight transposes (blocks 0..191) + LN1 (blocks 192..703) ----------------
__global__ __launch_bounds__(256) void prep_ln1_kernel(
    const float* __restrict__ qkv_w, const float* __restrict__ proj_w,
    const float* __restrict__ w1, const float* __restrict__ w2,
    bf16* __restrict__ wt_qkv, bf16* __restrict__ wt_proj,
    bf16* __restrict__ wt_w1, bf16* __restrict__ wt_w2,
    const float* __restrict__ x, const float* __restrict__ g,
    const float* __restrict__ b, bf16* __restrict__ ln1out)
{
    __shared__ __align__(16) char smem[35840];
    int bi = blockIdx.x;
    int tid = threadIdx.x;

    if (bi < 192) {
        // ---- weight transpose: src[K][M] -> dst[M][K] bf16 ----
        float (*tile)[33] = (float(*)[33])smem;   // 32*33*4 = 4224 B
        const float* src; bf16* dst; int K, M, t;
        if (bi < 48)       { src = qkv_w;  dst = wt_qkv;  K = 128; M = 384; t = bi; }
        else if (bi < 64)  { src = proj_w; dst = wt_proj; K = 128; M = 128; t = bi - 48; }
        else if (bi < 128) { src = w1;     dst = wt_w1;   K = 128; M = 512; t = bi - 64; }
        else               { src = w2;     dst = wt_w2;   K = 512; M = 128; t = bi - 128; }
        int tiles_x = M >> 5;
        int m0 = (t % tiles_x) * 32, k0 = (t / tiles_x) * 32;
        int tx = tid & 31, ty = tid >> 5;
        #pragma unroll
        for (int i = 0; i < 4; i++)
            tile[ty + i * 8][tx] = src[(size_t)(k0 + ty + i * 8) * M + m0 + tx];
        __syncthreads();
        #pragma unroll
        for (int i = 0; i < 4; i++)
            dst[(size_t)(m0 + ty + i * 8) * K + k0 + tx] = __float2bfloat16(tile[tx][ty + i * 8]);
        return;
    }

    // ---- LN1: transpose (C,N)->(N,C) + layernorm over C, out bf16 ----
    float (*tile)[65] = (float(*)[65])smem;               // 128*65*4 = 33280
    float (*red)[64][4] = (float(*)[64][4])(smem + 33280); // 2*64*4*4 = 2048 -> 35328
    float* smu = (float*)(smem + 35328);                   // 256
    float* srs = (float*)(smem + 35584);                   // 256 -> 35840
    int n0 = (bi - 192) * 64;
    #pragma unroll
    for (int i = 0; i < 32; i++) {
        int idx = i * 256 + tid;
        int c = idx >> 6, nn = idx & 63;
        tile[c][nn] = x[(size_t)c * NPOS + n0 + nn];
    }
    __syncthreads();
    {
        int p = tid >> 2, s = tid & 3;
        float sum = 0.f, ssq = 0.f;
        #pragma unroll
        for (int i = 0; i < 32; i++) {
            float v = tile[s * 32 + i][p];
            sum += v; ssq += v * v;
        }
        red[0][p][s] = sum; red[1][p][s] = ssq;
    }
    __syncthreads();
    if (tid < 64) {
        float s = red[0][tid][0] + red[0][tid][1] + red[0][tid][2] + red[0][tid][3];
        float q = red[1][tid][0] + red[1][tid][1] + red[1][tid][2] + red[1][tid][3];
        float mu = s * (1.f / 128.f);
        float var = q * (1.f / 128.f) - mu * mu;
        smu[tid] = mu;
        srs[tid] = rsqrtf(var + 1e-5f);
    }
    __syncthreads();
    #pragma unroll
    for (int i = 0; i < 32; i++) {
        int idx = i * 256 + tid;
        int nn = idx >> 7, c = idx & 127;
        ln1out[(size_t)(n0 + nn) * 128 + c] =
            __float2bfloat16((tile[c][nn] - smu[nn]) * srs[nn] * g[c] + b[c]);
    }
}

// ---------------- bf16 MFMA GEMM, BK=64, software-pipelined staging ----------------
// MODE 0: bf16 outb = acc + bias                     (QKV)
// MODE 2: bf16 outb = gelu(acc + bias)               (MLP1)
// MODE 3: f32 outf[c*N+r] = acc+bias+aux1b(x1,bf16)[r*128+c]+aux0(x)[c*N+r]   (MLP2->skip)
// MODE 4: proj+LN2: v=acc+bias+aux0[c*N+r]; outb(x1,bf16)[r*128+c]=v; row-LN(v) -> outb2 bf16
__device__ __forceinline__ float gelu_f(float v) {
    float u = 0.7978845608028654f * (v + 0.044715f * v * v * v);
    return v / (1.f + __expf(-2.f * u));
}

template<int MODE, int KT, int BM>
__global__ __launch_bounds__(256) void gemm_mfma_kernel(
    const bf16* __restrict__ A, const bf16* __restrict__ Bt,
    const float* __restrict__ bias, float* __restrict__ outf, bf16* __restrict__ outb,
    bf16* __restrict__ outb2,
    const float* __restrict__ aux0, const bf16* __restrict__ aux1b,
    const float* __restrict__ lng, const float* __restrict__ lnb,
    int N, int M)
{
    constexpr int MF = BM / 32;
    constexpr int NSTEP = KT / 64;
    constexpr int SMEM_BYTES = BM * 144 + 128 * 144;
    __shared__ __align__(16) char smem[SMEM_BYTES];
    bf16 (*As)[72] = (bf16(*)[72])smem;
    bf16 (*Bs)[72] = (bf16(*)[72])(smem + BM * 144);

    int tid = threadIdx.x;
    int row0 = blockIdx.x * BM;
    int col0 = blockIdx.y * 128;
    int lane = tid & 63, wid = tid >> 6;
    int wr = wid >> 1, wc = wid & 1;
    int lr = lane & 15, kg = lane >> 4;

    f32x4 acc[MF][4] = {};
    bf16x8 ra[MF], rb[4];

    #pragma unroll
    for (int i = 0; i < MF; i++) {
        int c = tid + i * 256;
        ra[i] = *(const bf16x8*)(A + (size_t)(row0 + (c >> 3)) * KT + (c & 7) * 8);
    }
    #pragma unroll
    for (int i = 0; i < 4; i++) {
        int c = tid + i * 256;
        rb[i] = *(const bf16x8*)(Bt + (size_t)(col0 + (c >> 3)) * KT + (c & 7) * 8);
    }

    for (int s = 0; s < NSTEP; s++) {
        if (s > 0) __syncthreads();
        #pragma unroll
        for (int i = 0; i < MF; i++) {
            int c = tid + i * 256;
            *(bf16x8*)&As[c >> 3][(c & 7) * 8] = ra[i];
        }
        #pragma unroll
        for (int i = 0; i < 4; i++) {
            int c = tid + i * 256;
            *(bf16x8*)&Bs[c >> 3][(c & 7) * 8] = rb[i];
        }
        __syncthreads();
        if (s + 1 < NSTEP) {
            int k0 = (s + 1) * 64;
            #pragma unroll
            for (int i = 0; i < MF; i++) {
                int c = tid + i * 256;
                ra[i] = *(const bf16x8*)(A + (size_t)(row0 + (c >> 3)) * KT + k0 + (c & 7) * 8);
            }
            #pragma unroll
            for (int i = 0; i < 4; i++) {
                int c = tid + i * 256;
                rb[i] = *(const bf16x8*)(Bt + (size_t)(col0 + (c >> 3)) * KT + k0 + (c & 7) * 8);
            }
        }
        #pragma unroll
        for (int ks = 0; ks < 2; ks++) {
            bf16x8 af[MF], bf_[4];
            #pragma unroll
            for (int m = 0; m < MF; m++)
                af[m] = *(const bf16x8*)&As[wr * (BM / 2) + m * 16 + lr][ks * 32 + kg * 8];
            #pragma unroll
            for (int n = 0; n < 4; n++)
                bf_[n] = *(const bf16x8*)&Bs[wc * 64 + n * 16 + lr][ks * 32 + kg * 8];
            #pragma unroll
            for (int m = 0; m < MF; m++)
                #pragma unroll
                for (int n = 0; n < 4; n++)
                    acc[m][n] = __builtin_amdgcn_mfma_f32_16x16x32_bf16(af[m], bf_[n], acc[m][n], 0, 0, 0);
        }
    }

    if (MODE == 0 || MODE == 2 || MODE == 3) {
        #pragma unroll
        for (int m = 0; m < MF; m++) {
            #pragma unroll
            for (int n = 0; n < 4; n++) {
                int c = col0 + wc * 64 + n * 16 + lr;
                float bv = bias[c];
                #pragma unroll
                for (int j = 0; j < 4; j++) {
                    int r = row0 + wr * (BM / 2) + m * 16 + kg * 4 + j;
                    float v = acc[m][n][j] + bv;
                    if (MODE == 0) {
                        outb[(size_t)r * M + c] = __float2bfloat16(v);
                    } else if (MODE == 2) {
                        outb[(size_t)r * M + c] = __float2bfloat16(gelu_f(v));
                    } else {
                        v += __bfloat162float(aux1b[(size_t)r * 128 + c]) + aux0[(size_t)c * N + r];
                        outf[(size_t)c * N + r] = v;
                    }
                }
            }
        }
    } else {
        // MODE 4: proj epilogue + fused LN2 (BM == 64, col0 == 0, M == 128 == full row)
        __syncthreads();
        float (*rsum)[33] = (float(*)[33])smem;               // 64*33*4 = 8448
        float (*rsq)[33]  = (float(*)[33])(smem + 8448);      // -> 16896
        float* smu = (float*)(smem + 16896);
        float* srs = (float*)(smem + 17152);
        int slot = wc * 16 + lr;
        #pragma unroll
        for (int m = 0; m < MF; m++) {
            #pragma unroll
            for (int j = 0; j < 4; j++) {
                int rloc = wr * (BM / 2) + m * 16 + kg * 4 + j;
                int r = row0 + rloc;
                float ps = 0.f, pq = 0.f;
                #pragma unroll
                for (int n = 0; n < 4; n++) {
                    int c = wc * 64 + n * 16 + lr;
                    float v = acc[m][n][j] + bias[c] + aux0[(size_t)c * N + r];
                    acc[m][n][j] = v;
                    outb[(size_t)r * 128 + c] = __float2bfloat16(v);   // x1 (bf16)
                    ps += v; pq += v * v;
                }
                rsum[rloc][slot] = ps;
                rsq[rloc][slot]  = pq;
            }
        }
        __syncthreads();
        if (tid < 64) {
            float s = 0.f, q = 0.f;
            #pragma unroll
            for (int i = 0; i < 32; i++) { s += rsum[tid][i]; q += rsq[tid][i]; }
            float mu = s * (1.f / 128.f);
            float var = q * (1.f / 128.f) - mu * mu;
            smu[tid] = mu;
            srs[tid] = rsqrtf(var + 1e-5f);
        }
        __syncthreads();
        #pragma unroll
        for (int m = 0; m < MF; m++) {
            #pragma unroll
            for (int j = 0; j < 4; j++) {
                int rloc = wr * (BM / 2) + m * 16 + kg * 4 + j;
                int r = row0 + rloc;
                float mu = smu[rloc], rs = srs[rloc];
                #pragma unroll
                for (int n = 0; n < 4; n++) {
                    int c = wc * 64 + n * 16 + lr;
                    float v = (acc[m][n][j] - mu) * rs * lng[c] + lnb[c];
                    outb2[(size_t)r * 128 + c] = __float2bfloat16(v);
                }
            }
        }
    }
}

// ---------------- neighborhood attention: 1 thread per (position, head), NO LDS ----------------
__global__ __launch_bounds__(256) void attn_kernel(
    const bf16* __restrict__ qkv,   // [N][384]  (q|k|v)
    const float* __restrict__ rpb,  // [8][5][5][5]
    bf16* __restrict__ out)         // [N][128]
{
    int t = blockIdx.x * 256 + threadIdx.x;
    int head = t & 7, n = t >> 3;
    int z = n & 7, w = (n >> 3) & 63, h = n >> 9;

    int sh = min(max(h - 1, 0), 61);
    int sw = min(max(w - 1, 0), 61);
    int sz = min(max(z - 1, 0), 5);

    float qf[16];
    {
        const bf16* qp = qkv + (size_t)n * 384 + head * 16;
        bf16x8 q0 = *(const bf16x8*)qp;
        bf16x8 q1 = *(const bf16x8*)(qp + 8);
        #pragma unroll
        for (int e = 0; e < 8; e++) {
            qf[e]     = bf2f(q0[e]) * 0.25f;
            qf[e + 8] = bf2f(q1[e]) * 0.25f;
        }
    }

    const bf16*  kbase = qkv + (size_t)((sh << 9) + (sw << 3) + sz) * 384 + 128 + head * 16;
    const float* rp    = rpb + head * 125 + (sh - h + 2) * 25 + (sw - w + 2) * 5 + (sz - z + 2);

    float sc[27];
    float mx = -1e30f;
    #pragma unroll
    for (int a = 0; a < 3; a++) {
        #pragma unroll
        for (int b = 0; b < 3; b++) {
            #pragma unroll
            for (int c = 0; c < 3; c++) {
                const bf16* kp = kbase + (size_t)(a * 512 + b * 8 + c) * 384;
                bf16x8 k0 = *(const bf16x8*)kp;
                bf16x8 k1 = *(const bf16x8*)(kp + 8);
                float s = 0.f;
                #pragma unroll
                for (int e = 0; e < 8; e++) s = fmaf(qf[e], bf2f(k0[e]), s);
                #pragma unroll
                for (int e = 0; e < 8; e++) s = fmaf(qf[e + 8], bf2f(k1[e]), s);
                s += rp[a * 25 + b * 5 + c];
                sc[a * 9 + b * 3 + c] = s;
                mx = fmaxf(mx, s);
            }
        }
    }

    float sum = 0.f;
    #pragma unroll
    for (int m = 0; m < 27; m++) {
        float e = __expf(sc[m] - mx);
        sc[m] = e;
        sum += e;
    }
    float inv = 1.f / sum;

    float o[16] = {};
    #pragma unroll
    for (int a = 0; a < 3; a++) {
        #pragma unroll
        for (int b = 0; b < 3; b++) {
            #pragma unroll
            for (int c = 0; c < 3; c++) {
                const bf16* vp = kbase + (size_t)(a * 512 + b * 8 + c) * 384 + 128;
                bf16x8 v0 = *(const bf16x8*)vp;
                bf16x8 v1 = *(const bf16x8*)(vp + 8);
                float pm = sc[a * 9 + b * 3 + c];
                #pragma unroll
                for (int e = 0; e < 8; e++) {
                    o[e]     = fmaf(pm, bf2f(v0[e]), o[e]);
                    o[e + 8] = fmaf(pm, bf2f(v1[e]), o[e + 8]);
                }
            }
        }
    }

    short os[16];
    #pragma unroll
    for (int e = 0; e < 16; e++) {
        union { bf16 b; short s; } cv;
        cv.b = __float2bfloat16(o[e] * inv);
        os[e] = cv.s;
    }
    bf16* op = out + (size_t)n * 128 + head * 16;
    *(bf16x8*)op       = *(bf16x8*)os;
    *(bf16x8*)(op + 8) = *(bf16x8*)(os + 8);
}

// ---------------- 2x2x2 maxpool over (H,W,Z) ----------------
__global__ __launch_bounds__(256) void pool_kernel(
    const float* __restrict__ skip, float* __restrict__ pooled)
{
    int t = blockIdx.x * 256 + threadIdx.x;
    if (t >= 128 * 32 * 32 * 4) return;
    int oz = t & 3, ow = (t >> 2) & 31, oh = (t >> 7) & 31, c = t >> 12;
    const float* base = skip + (size_t)c * 32768 + (oh * 2) * 512 + (ow * 2) * 8 + oz * 2;
    float m = -INFINITY;
    #pragma unroll
    for (int dh = 0; dh < 2; dh++)
        #pragma unroll
        for (int dw = 0; dw < 2; dw++)
            #pragma unroll
            for (int dz = 0; dz < 2; dz++)
                m = fmaxf(m, base[dh * 512 + dw * 8 + dz]);
    pooled[t] = m;
}

extern "C" void kernel_launch(void* const* d_in, const int* in_sizes, int n_in,
                              void* d_out, int out_size, void* d_ws, size_t ws_size,
                              hipStream_t stream) {
    const float* x      = (const float*)d_in[0];
    const float* ln1_g  = (const float*)d_in[1];
    const float* ln1_b  = (const float*)d_in[2];
    const float* qkv_w  = (const float*)d_in[3];
    const float* qkv_b  = (const float*)d_in[4];
    const float* proj_w = (const float*)d_in[5];
    const float* proj_b = (const float*)d_in[6];
    const float* rpb    = (const float*)d_in[7];
    const float* ln2_g  = (const float*)d_in[8];
    const float* ln2_b  = (const float*)d_in[9];
    const float* w1     = (const float*)d_in[10];
    const float* b1     = (const float*)d_in[11];
    const float* w2     = (const float*)d_in[12];
    const float* b2     = (const float*)d_in[13];

    const int N = NPOS;
    char* wsc = (char*)d_ws;
    bf16*  buf0  = (bf16*)wsc;                               // N*128 bf16: xn -> attn_out -> ln2out
    bf16*  buf1  = (bf16*)(wsc + (size_t)N * 128 * 2);       // N*512 bf16: qkv(384) -> hidden(512)
    bf16*  buf2b = (bf16*)(wsc + (size_t)N * 128 * 2 + (size_t)N * 512 * 2);  // N*128 bf16: x1
    char*  wts   = wsc + (size_t)N * 128 * 2 + (size_t)N * 512 * 2 + (size_t)N * 128 * 2;
    bf16* wt_qkv  = (bf16*)wts;                 // [384][128]
    bf16* wt_proj = wt_qkv  + 384 * 128;        // [128][128]
    bf16* wt_w1   = wt_proj + 128 * 128;        // [512][128]
    bf16* wt_w2   = wt_w1   + 512 * 128;        // [128][512]

    float* out_pooled = (float*)d_out;
    float* out_skip   = (float*)d_out + 524288;

    // 0+1. weight transposes + LN1 in ONE dispatch (independent work, 704 blocks)
    prep_ln1_kernel<<<704, 256, 0, stream>>>(qkv_w, proj_w, w1, w2,
                                             wt_qkv, wt_proj, wt_w1, wt_w2,
                                             x, ln1_g, ln1_b, buf0);

    // 2. QKV GEMM: [N,128] @ [128,384] -> bf16
    gemm_mfma_kernel<0, 128, 128><<<dim3(N / 128, 3), 256, 0, stream>>>(
        buf0, wt_qkv, qkv_b, nullptr, buf1, nullptr, nullptr, nullptr, nullptr, nullptr, N, 384);

    // 3. neighborhood attention -> bf16 (no LDS, 1 thread per (pos,head))
    attn_kernel<<<(N * 8) / 256, 256, 0, stream>>>(buf1, rpb, buf0);

    // 4. proj GEMM + residual + fused LN2: x1(bf16)->buf2b, ln2out(bf16)->buf0
    gemm_mfma_kernel<4, 128, 64><<<dim3(N / 64, 1), 256, 0, stream>>>(
        buf0, wt_proj, proj_b, nullptr, buf2b, buf0, x, nullptr, ln2_g, ln2_b, N, 128);

    // 5. MLP1 + gelu: [N,128] @ [128,512] -> bf16
    gemm_mfma_kernel<2, 128, 128><<<dim3(N / 128, 4), 256, 0, stream>>>(
        buf0, wt_w1, b1, nullptr, buf1, nullptr, nullptr, nullptr, nullptr, nullptr, N, 512);

    // 6. MLP2 + bias + x1 + x -> skip (transposed fp32 write into d_out)
    gemm_mfma_kernel<3, 512, 64><<<dim3(N / 64, 1), 256, 0, stream>>>(
        buf1, wt_w2, b2, out_skip, nullptr, nullptr, x, buf2b, nullptr, nullptr, N, 128);

    // 7. maxpool -> pooled
    pool_kernel<<<(524288 + 255) / 256, 256, 0, stream>>>(out_skip, out_pooled);
}